// Round 2
// baseline (1231.733 us; speedup 1.0000x reference)
//
#include <hip/hip_runtime.h>
#include <hip/hip_bf16.h>

#define NN 2048
#define EE 4096
#define LL 49
#define LRR 16
#define NYY 3
#define CC 128
#define HH 128

__device__ __forceinline__ float siluf(float v) { return v * (1.0f / (1.0f + __expf(-v))); }

// ---------------- per-node channel mean: xmean[n][l] = mean_c x[n,l,c] ----------------
__global__ __launch_bounds__(256) void node_mean_kernel(const float* __restrict__ x,
                                                        float* __restrict__ xmean) {
  int row = blockIdx.x * 4 + (threadIdx.x >> 6);   // row in [0, NN*LL)
  int lane = threadIdx.x & 63;
  const float* p = x + (long)row * CC;
  float s = p[lane] + p[lane + 64];
  for (int off = 32; off > 0; off >>= 1) s += __shfl_down(s, off);
  if (lane == 0) xmean[row] = s * (1.0f / 128.0f);
}

// ---------------- per-edge CG scalars: mid (LDS-only), asum = a21 + a22 ----------------
__global__ __launch_bounds__(256) void edge_scalar_kernel(
    const float* __restrict__ xmean, const int* __restrict__ eidx,
    const float* __restrict__ Wcg1, const float* __restrict__ Wcg21,
    const float* __restrict__ Wcg22, float* __restrict__ asum) {
  __shared__ float sxm[4][49], sym[4][49], smid[4][32];
  int el = threadIdx.x >> 6, o = threadIdx.x & 63;
  int e = blockIdx.x * 4 + el;
  int s = eidx[e], d = eidx[EE + e];
  if (o < 49) { sxm[el][o] = xmean[s * 49 + o]; sym[el][o] = xmean[d * 49 + o]; }
  __syncthreads();
  if (o < 25) {
    float acc = 0.f;
    for (int i = 0; i < 49; ++i) {
      float xi = sxm[el][i];
      const float* w = Wcg1 + (i * 49) * 25 + o;
      for (int j = 0; j < 49; ++j) acc += xi * sym[el][j] * w[j * 25];
    }
    smid[el][o] = acc;
  }
  __syncthreads();
  if (o < 49) {
    float a = 0.f;
    for (int i = 0; i < 49; ++i) {
      float xi = sxm[el][i], yi = sym[el][i];
      const float* w1 = Wcg21 + (i * 25) * 49 + o;
      const float* w2 = Wcg22 + (i * 25) * 49 + o;
      for (int j = 0; j < 25; ++j) {
        float mj = smid[el][j];
        a += mj * (xi * w1[j * 49] + yi * w2[j * 49]);
      }
    }
    asum[e * 49 + o] = a;
  }
}

// ---------------- per-edge feat build: wig_node^T rotation + rowmean*glovec feature ----------------
__global__ __launch_bounds__(256) void build_feat_kernel(
    const float* __restrict__ x, const float* __restrict__ x_glovec,
    const float* __restrict__ wig_node, const int* __restrict__ eidx,
    float* __restrict__ feat1, float* __restrict__ feat2) {
  __shared__ float wig[256];
  __shared__ float xa[2048], xb[2048], tmp[2048];
  int e = blockIdx.x, tid = threadIdx.x;
  int s = eidx[e], d = eidx[EE + e];
  wig[tid] = wig_node[e * 256 + tid];
  for (int idx = tid; idx < 2048; idx += 256) {
    int l = idx >> 7, c = idx & 127;
    xa[idx] = x[((long)s * LL + l) * CC + c];
    xb[idx] = x[((long)d * LL + l) * CC + c];
  }
  __syncthreads();
  // pass 1: ne = xs, ndf = glovec[dst]
  for (int idx = tid; idx < 2048; idx += 256) {
    int i = idx >> 7, c = idx & 127;
    float a = 0.f;
#pragma unroll
    for (int j = 0; j < 16; ++j) a += wig[j * 16 + i] * xa[j * 128 + c];
    tmp[idx] = a;
    feat1[(long)e * 2064 + i * 129 + c] = a;
  }
  __syncthreads();
  if (tid < 16) {
    float m = 0.f;
    for (int c = 0; c < 128; ++c) m += tmp[tid * 128 + c];
    m *= (1.0f / 128.0f);
    feat1[(long)e * 2064 + tid * 129 + 128] = m * x_glovec[(long)d * 16 + tid];
  }
  __syncthreads();
  // pass 2: ne = xt, ndf = glovec[src]
  for (int idx = tid; idx < 2048; idx += 256) {
    int i = idx >> 7, c = idx & 127;
    float a = 0.f;
#pragma unroll
    for (int j = 0; j < 16; ++j) a += wig[j * 16 + i] * xb[j * 128 + c];
    tmp[idx] = a;
    feat2[(long)e * 2064 + i * 129 + c] = a;
  }
  __syncthreads();
  if (tid < 16) {
    float m = 0.f;
    for (int c = 0; c < 128; ++c) m += tmp[tid * 128 + c];
    m *= (1.0f / 128.0f);
    feat2[(long)e * 2064 + tid * 129 + 128] = m * x_glovec[(long)s * 16 + tid];
  }
}

// ---------------- generic fp32 tiled GEMM: C = epi(A[MxK] @ B[KxN] + bias) ----------------
template <bool SILU, bool XE>
__global__ __launch_bounds__(256) void gemm_f32(
    const float* __restrict__ A, const float* __restrict__ B,
    const float* __restrict__ bias, const float* __restrict__ xe,
    float* __restrict__ C, int M, int N, int K) {
  __shared__ float As[16][68];  // [k][m], padded; row stride 272B (16B multiple)
  __shared__ float Bs[16][64];  // [k][n]
  const int tid = threadIdx.x;
  const int bm = blockIdx.x * 64, bn = blockIdx.y * 64;
  const int tx = tid & 15, ty = tid >> 4;
  const int ar = tid >> 2;          // m within tile
  const int ak = (tid & 3) * 4;     // k within tile
  const int br = tid >> 4;          // k within tile
  const int bc = (tid & 15) * 4;    // n within tile
  float acc[4][4] = {};
  const float* Ap = A + (long)(bm + ar) * K + ak;
  const float* Bp = B + (long)br * N + bn + bc;
  for (int k0 = 0; k0 < K; k0 += 16) {
    const float4 av = *(const float4*)(Ap + k0);
    const float4 bv = *(const float4*)(Bp + (long)k0 * N);
    __syncthreads();
    As[ak + 0][ar] = av.x; As[ak + 1][ar] = av.y;
    As[ak + 2][ar] = av.z; As[ak + 3][ar] = av.w;
    *(float4*)&Bs[br][bc] = bv;
    __syncthreads();
#pragma unroll
    for (int k = 0; k < 16; ++k) {
      const float4 a = *(const float4*)&As[k][ty * 4];
      const float4 b = *(const float4*)&Bs[k][tx * 4];
      acc[0][0] += a.x * b.x; acc[0][1] += a.x * b.y; acc[0][2] += a.x * b.z; acc[0][3] += a.x * b.w;
      acc[1][0] += a.y * b.x; acc[1][1] += a.y * b.y; acc[1][2] += a.y * b.z; acc[1][3] += a.y * b.w;
      acc[2][0] += a.z * b.x; acc[2][1] += a.z * b.y; acc[2][2] += a.z * b.z; acc[2][3] += a.z * b.w;
      acc[3][0] += a.w * b.x; acc[3][1] += a.w * b.y; acc[3][2] += a.w * b.z; acc[3][3] += a.w * b.w;
    }
  }
#pragma unroll
  for (int i = 0; i < 4; ++i) {
    int row = bm + ty * 4 + i;
#pragma unroll
    for (int j = 0; j < 4; ++j) {
      int col = bn + tx * 4 + j;
      float v = acc[i][j] + bias[col];
      if (SILU) v = siluf(v);
      if (XE) v *= xe[(row / 3) * HH + col];
      C[(long)row * N + col] = v;
    }
  }
}

// ---------------- sh = wig_node @ (o1 + o2) ----------------
__global__ __launch_bounds__(256) void rotback_kernel(
    const float* __restrict__ wig_node, const float* __restrict__ o1,
    const float* __restrict__ o2, float* __restrict__ sh) {
  __shared__ float wig[256];
  __shared__ float osum[2048];
  int e = blockIdx.x, tid = threadIdx.x;
  wig[tid] = wig_node[e * 256 + tid];
  for (int idx = tid; idx < 2048; idx += 256)
    osum[idx] = o1[(long)e * 2048 + idx] + o2[(long)e * 2048 + idx];
  __syncthreads();
  for (int idx = tid; idx < 2048; idx += 256) {
    int i = idx >> 7, c = idx & 127;
    float a = 0.f;
#pragma unroll
    for (int j = 0; j < 16; ++j) a += wig[i * 16 + j] * osum[j * 128 + c];
    sh[(long)e * 2048 + idx] = a;
  }
}

// ---------------- msg = wigner @ z, z = 2(xs+xt) + asum + pad(sh) ----------------
__global__ __launch_bounds__(256) void rotate_msg_kernel(
    const float* __restrict__ x, const float* __restrict__ wigner,
    const int* __restrict__ eidx, const float* __restrict__ asum,
    const float* __restrict__ sh, float* __restrict__ msg) {
  __shared__ float z[49 * 128];
  __shared__ float wg[2352];
  __shared__ float as_s[49];
  int e = blockIdx.x, tid = threadIdx.x;
  int s = eidx[e], d = eidx[EE + e];
  if (tid < 49) as_s[tid] = asum[e * 49 + tid];
  for (int idx = tid; idx < 2352; idx += 256) wg[idx] = wigner[(long)e * 2352 + idx];
  __syncthreads();
  for (int idx = tid; idx < 6272; idx += 256) {
    int l = idx >> 7, c = idx & 127;
    float v = 2.0f * (x[((long)s * LL + l) * CC + c] + x[((long)d * LL + l) * CC + c]) + as_s[l];
    if (l < 16) v += sh[(long)e * 2048 + l * 128 + c];
    z[idx] = v;
  }
  __syncthreads();
  for (int idx = tid; idx < 6144; idx += 256) {
    int ny = idx >> 11, rc = idx & 2047, c = rc & 127;
    const float* w = wg + ny * 784 + (rc >> 7) * 49;
    float a = 0.f;
#pragma unroll
    for (int b = 0; b < 49; ++b) a += w[b] * z[b * 128 + c];
    msg[((long)e * 3 + ny) * 2048 + rc] = a;
  }
}

// ---------------- out = INV_SQRT_3 * wigner_inv @ mean_ny(m2) ----------------
__global__ __launch_bounds__(256) void out_kernel(
    const float* __restrict__ m2, const float* __restrict__ wigner_inv,
    float* __restrict__ out) {
  __shared__ float mr[2048];
  __shared__ float wv[784];
  int e = blockIdx.x, tid = threadIdx.x;
  for (int idx = tid; idx < 2048; idx += 256)
    mr[idx] = (m2[((long)e * 3 + 0) * 2048 + idx] + m2[((long)e * 3 + 1) * 2048 + idx] +
               m2[((long)e * 3 + 2) * 2048 + idx]) * (1.0f / 3.0f);
  for (int idx = tid; idx < 784; idx += 256) wv[idx] = wigner_inv[(long)e * 784 + idx];
  __syncthreads();
  for (int idx = tid; idx < 6272; idx += 256) {
    int bq = idx >> 7, c = idx & 127;
    const float* w = wv + bq * 16;
    float a = 0.f;
#pragma unroll
    for (int r = 0; r < 16; ++r) a += w[r] * mr[r * 128 + c];
    out[(long)e * 6272 + idx] = a * 0.57735026918962576f;
  }
}

// ---------------- host side ----------------
extern "C" void kernel_launch(void* const* d_in, const int* in_sizes, int n_in,
                              void* d_out, int out_size, void* d_ws, size_t ws_size,
                              hipStream_t stream) {
  (void)in_sizes; (void)n_in; (void)out_size; (void)ws_size;
  const float* x        = (const float*)d_in[0];
  const float* x_glovec = (const float*)d_in[2];
  const float* x_edge   = (const float*)d_in[3];
  const int*   eidx     = (const int*)d_in[4];
  const float* W_cg1   = (const float*)d_in[8];
  const float* W_cg21  = (const float*)d_in[9];
  const float* W_cg22  = (const float*)d_in[10];
  const float* Wn1a = (const float*)d_in[11];
  const float* bn1a = (const float*)d_in[12];
  const float* Wn1b = (const float*)d_in[13];
  const float* bn1b = (const float*)d_in[14];
  const float* Wn2a = (const float*)d_in[15];
  const float* bn2a = (const float*)d_in[16];
  const float* Wn2b = (const float*)d_in[17];
  const float* bn2b = (const float*)d_in[18];
  const float* Wd   = (const float*)d_in[19];
  const float* bd   = (const float*)d_in[20];
  const float* Wp1  = (const float*)d_in[21];
  const float* bp1  = (const float*)d_in[22];
  const float* Wp2  = (const float*)d_in[23];
  const float* bp2  = (const float*)d_in[24];
  const float* wigner     = (const float*)d_in[25];
  const float* wigner_inv = (const float*)d_in[26];
  const float* wig_node   = (const float*)d_in[27];

  float* ws = (float*)d_ws;
  // workspace layout (element offsets, fp32); total 52,336,640 floats (~209 MB)
  float* p_xmean = ws + 0;                    // 100352
  float* p_xe    = ws + 100352;               // 524288
  float* p_asum  = ws + 624640;               // 200704
  float* p_feat1 = ws + 825344;               // 8454144
  float* p_feat2 = ws + 9279488;              // 8454144
  float* p_h1    = ws + 17733632;             // 524288
  float* p_h2    = ws + 18257920;             // 524288
  float* p_sh    = ws + 18782208;             // 8388608
  float* p_msg   = ws + 27170816;             // 25165824
  float* p_o1    = p_feat1;                   // alias (feat1 dead after h1 GEMM)
  float* p_o2    = p_feat2;                   // alias (feat2 dead after h2 GEMM)
  float* p_m1    = p_sh;                      // alias (sh dead after rotate_msg)
  float* p_m2    = p_msg;                     // alias (msg dead after m1 GEMM)

  node_mean_kernel<<<(NN * LL) / 4, 256, 0, stream>>>(x, p_xmean);
  edge_scalar_kernel<<<EE / 4, 256, 0, stream>>>(p_xmean, eidx, W_cg1, W_cg21, W_cg22, p_asum);
  // xe = silu(x_edge @ Wd + bd)
  gemm_f32<true, false><<<dim3(EE / 64, HH / 64), 256, 0, stream>>>(
      x_edge, Wd, bd, nullptr, p_xe, EE, HH, 128);
  build_feat_kernel<<<EE, 256, 0, stream>>>(x, x_glovec, wig_node, eidx, p_feat1, p_feat2);
  // h = silu(feat @ Wa + ba)
  gemm_f32<true, false><<<dim3(EE / 64, HH / 64), 256, 0, stream>>>(
      p_feat1, Wn1a, bn1a, nullptr, p_h1, EE, HH, 2064);
  gemm_f32<true, false><<<dim3(EE / 64, HH / 64), 256, 0, stream>>>(
      p_feat2, Wn2a, bn2a, nullptr, p_h2, EE, HH, 2064);
  // o = silu(h @ Wb + bb)
  gemm_f32<true, false><<<dim3(EE / 64, 2048 / 64), 256, 0, stream>>>(
      p_h1, Wn1b, bn1b, nullptr, p_o1, EE, 2048, 128);
  gemm_f32<true, false><<<dim3(EE / 64, 2048 / 64), 256, 0, stream>>>(
      p_h2, Wn2b, bn2b, nullptr, p_o2, EE, 2048, 128);
  rotback_kernel<<<EE, 256, 0, stream>>>(wig_node, p_o1, p_o2, p_sh);
  rotate_msg_kernel<<<EE, 256, 0, stream>>>(x, wigner, eidx, p_asum, p_sh, p_msg);
  // m1 = silu(msg @ Wp1 + bp1) * xe
  gemm_f32<true, true><<<dim3(12288 / 64, HH / 64), 256, 0, stream>>>(
      p_msg, Wp1, bp1, p_xe, p_m1, 12288, HH, 2048);
  // m2 = silu(m1 @ Wp2 + bp2)
  gemm_f32<true, false><<<dim3(12288 / 64, 2048 / 64), 256, 0, stream>>>(
      p_m1, Wp2, bp2, nullptr, p_m2, 12288, 2048, 128);
  out_kernel<<<EE, 256, 0, stream>>>(p_m2, wigner_inv, (float*)d_out);
}

// Round 3
// 758.652 us; speedup vs baseline: 1.6236x; 1.6236x over previous
//
#include <hip/hip_runtime.h>
#include <hip/hip_bf16.h>

typedef __hip_bfloat16 bf16;
typedef __attribute__((ext_vector_type(8))) short short8;
typedef __attribute__((ext_vector_type(4))) float f32x4;

#define NN 2048
#define EE 4096
#define LL 49
#define LRR 16
#define NYY 3
#define CC 128
#define HH 128

__device__ __forceinline__ float siluf(float v) { return v * (1.0f / (1.0f + __expf(-v))); }
__device__ __forceinline__ bf16 f2b(float v) { return __float2bfloat16(v); }

// ---------------- weight convert + transpose: out[n*Kp+k] = bf16(in[k*N+n]), zero-pad k>=K ----------------
struct TJob { const float* in; bf16* out; int K, N, Kp; };
struct TJobs { TJob j[6]; };

__global__ __launch_bounds__(256) void transpose_cvt_kernel(TJobs jobs) {
  TJob jb = jobs.j[blockIdx.y];
  int i = blockIdx.x * 256 + threadIdx.x;
  if (i < jb.N * jb.Kp) {
    int n = i / jb.Kp, k = i - n * jb.Kp;
    jb.out[i] = (k < jb.K) ? f2b(jb.in[(long)k * jb.N + n]) : f2b(0.f);
  }
}

// ---------------- per-node channel mean ----------------
__global__ __launch_bounds__(256) void node_mean_kernel(const float* __restrict__ x,
                                                        float* __restrict__ xmean) {
  int row = blockIdx.x * 4 + (threadIdx.x >> 6);
  int lane = threadIdx.x & 63;
  const float* p = x + (long)row * CC;
  float s = p[lane] + p[lane + 64];
  for (int off = 32; off > 0; off >>= 1) s += __shfl_down(s, off);
  if (lane == 0) xmean[row] = s * (1.0f / 128.0f);
}

// ---------------- per-edge CG scalars ----------------
__global__ __launch_bounds__(256) void edge_scalar_kernel(
    const float* __restrict__ xmean, const int* __restrict__ eidx,
    const float* __restrict__ Wcg1, const float* __restrict__ Wcg21,
    const float* __restrict__ Wcg22, float* __restrict__ asum) {
  __shared__ float sxm[4][49], sym[4][49], smid[4][32];
  int el = threadIdx.x >> 6, o = threadIdx.x & 63;
  int e = blockIdx.x * 4 + el;
  int s = eidx[e], d = eidx[EE + e];
  if (o < 49) { sxm[el][o] = xmean[s * 49 + o]; sym[el][o] = xmean[d * 49 + o]; }
  __syncthreads();
  if (o < 25) {
    float acc = 0.f;
    for (int i = 0; i < 49; ++i) {
      float xi = sxm[el][i];
      const float* w = Wcg1 + (i * 49) * 25 + o;
      for (int j = 0; j < 49; ++j) acc += xi * sym[el][j] * w[j * 25];
    }
    smid[el][o] = acc;
  }
  __syncthreads();
  if (o < 49) {
    float a = 0.f;
    for (int i = 0; i < 49; ++i) {
      float xi = sxm[el][i], yi = sym[el][i];
      const float* w1 = Wcg21 + (i * 25) * 49 + o;
      const float* w2 = Wcg22 + (i * 25) * 49 + o;
      for (int j = 0; j < 25; ++j) {
        float mj = smid[el][j];
        a += mj * (xi * w1[j * 49] + yi * w2[j * 49]);
      }
    }
    asum[e * 49 + o] = a;
  }
}

// ---------------- feat build -> bf16 [8192][2112] (rows e, 4096+e), pad cols 2064..2111 = 0 ----------------
__global__ __launch_bounds__(256) void build_feat_kernel(
    const float* __restrict__ x, const float* __restrict__ x_glovec,
    const float* __restrict__ wig_node, const int* __restrict__ eidx,
    bf16* __restrict__ featst) {
  __shared__ float wig[256];
  __shared__ float xa[2048], xb[2048], tmp[2048];
  int e = blockIdx.x, tid = threadIdx.x;
  int s = eidx[e], d = eidx[EE + e];
  wig[tid] = wig_node[e * 256 + tid];
  if (tid < 48) {
    featst[(long)e * 2112 + 2064 + tid] = f2b(0.f);
    featst[(long)(EE + e) * 2112 + 2064 + tid] = f2b(0.f);
  }
  for (int idx = tid; idx < 2048; idx += 256) {
    int l = idx >> 7, c = idx & 127;
    xa[idx] = x[((long)s * LL + l) * CC + c];
    xb[idx] = x[((long)d * LL + l) * CC + c];
  }
  __syncthreads();
  for (int idx = tid; idx < 2048; idx += 256) {
    int i = idx >> 7, c = idx & 127;
    float a = 0.f;
#pragma unroll
    for (int j = 0; j < 16; ++j) a += wig[j * 16 + i] * xa[j * 128 + c];
    tmp[idx] = a;
    featst[(long)e * 2112 + i * 129 + c] = f2b(a);
  }
  __syncthreads();
  if (tid < 16) {
    float m = 0.f;
    for (int c = 0; c < 128; ++c) m += tmp[tid * 128 + c];
    featst[(long)e * 2112 + tid * 129 + 128] = f2b(m * (1.0f / 128.0f) * x_glovec[(long)d * 16 + tid]);
  }
  __syncthreads();
  for (int idx = tid; idx < 2048; idx += 256) {
    int i = idx >> 7, c = idx & 127;
    float a = 0.f;
#pragma unroll
    for (int j = 0; j < 16; ++j) a += wig[j * 16 + i] * xb[j * 128 + c];
    tmp[idx] = a;
    featst[(long)(EE + e) * 2112 + i * 129 + c] = f2b(a);
  }
  __syncthreads();
  if (tid < 16) {
    float m = 0.f;
    for (int c = 0; c < 128; ++c) m += tmp[tid * 128 + c];
    featst[(long)(EE + e) * 2112 + tid * 129 + 128] = f2b(m * (1.0f / 128.0f) * x_glovec[(long)s * 16 + tid]);
  }
}

// ---------------- fp32 tiled GEMM (only for tiny xe GEMM) ----------------
__global__ __launch_bounds__(256) void gemm_f32_silu(
    const float* __restrict__ A, const float* __restrict__ B,
    const float* __restrict__ bias, float* __restrict__ C, int M, int N, int K) {
  __shared__ float As[16][68];
  __shared__ float Bs[16][64];
  const int tid = threadIdx.x;
  const int bm = blockIdx.x * 64, bn = blockIdx.y * 64;
  const int tx = tid & 15, ty = tid >> 4;
  const int ar = tid >> 2, ak = (tid & 3) * 4;
  const int br = tid >> 4, bc = (tid & 15) * 4;
  float acc[4][4] = {};
  const float* Ap = A + (long)(bm + ar) * K + ak;
  const float* Bp = B + (long)br * N + bn + bc;
  for (int k0 = 0; k0 < K; k0 += 16) {
    const float4 av = *(const float4*)(Ap + k0);
    const float4 bv = *(const float4*)(Bp + (long)k0 * N);
    __syncthreads();
    As[ak + 0][ar] = av.x; As[ak + 1][ar] = av.y;
    As[ak + 2][ar] = av.z; As[ak + 3][ar] = av.w;
    *(float4*)&Bs[br][bc] = bv;
    __syncthreads();
#pragma unroll
    for (int k = 0; k < 16; ++k) {
      const float4 a = *(const float4*)&As[k][ty * 4];
      const float4 b = *(const float4*)&Bs[k][tx * 4];
      acc[0][0] += a.x * b.x; acc[0][1] += a.x * b.y; acc[0][2] += a.x * b.z; acc[0][3] += a.x * b.w;
      acc[1][0] += a.y * b.x; acc[1][1] += a.y * b.y; acc[1][2] += a.y * b.z; acc[1][3] += a.y * b.w;
      acc[2][0] += a.z * b.x; acc[2][1] += a.z * b.y; acc[2][2] += a.z * b.z; acc[2][3] += a.z * b.w;
      acc[3][0] += a.w * b.x; acc[3][1] += a.w * b.y; acc[3][2] += a.w * b.z; acc[3][3] += a.w * b.w;
    }
  }
#pragma unroll
  for (int i = 0; i < 4; ++i) {
    int row = bm + ty * 4 + i;
#pragma unroll
    for (int j = 0; j < 4; ++j) {
      int col = bn + tx * 4 + j;
      C[(long)row * N + col] = siluf(acc[i][j] + bias[col]);
    }
  }
}

// ---------------- bf16 MFMA GEMM: C = epi(A[MxK]bf16 @ BT[NxK]bf16^T + bias) ----------------
// Tile BMx128, BK=64; 4 waves as 2(m)x2(n); wave tile (BM/2)x64; 16x16x32 MFMA.
// LDS XOR-swizzle: element (row, k) -> row*64 + ((k/8) ^ (row&7))*8 + k%8.
template <int BM, bool SILU, bool XE, bool OUT_BF16>
__global__ __launch_bounds__(256) void gemm_mfma(
    const bf16* __restrict__ A, const bf16* __restrict__ B0, const bf16* __restrict__ B1,
    const float* __restrict__ bias0, const float* __restrict__ bias1,
    const float* __restrict__ xe, void* __restrict__ Cout,
    int M, int N, int K, int half) {
  constexpr int MI = BM / 32;
  __shared__ short As[BM * 64];
  __shared__ short Bs[128 * 64];
  const int tid = threadIdx.x;
  const int w = tid >> 6, lane = tid & 63;
  const int lm = lane & 15, q = lane >> 4;
  const int bm = blockIdx.x * BM, bn = blockIdx.y * 128;
  const int wm = (w & 1) * (BM / 2), wn = (w >> 1) * 64;
  const bf16* Bp = (bm < half) ? B0 : B1;
  const float* bias = (bm < half) ? bias0 : bias1;

  f32x4 acc[MI][4];
#pragma unroll
  for (int mi = 0; mi < MI; ++mi)
#pragma unroll
    for (int ni = 0; ni < 4; ++ni) acc[mi][ni] = (f32x4){0.f, 0.f, 0.f, 0.f};

  for (int k0 = 0; k0 < K; k0 += 64) {
    __syncthreads();
    // stage A: BM rows x 64 k (BM/32 iters of 256 threads x 16B)
#pragma unroll
    for (int it = 0; it < BM / 32; ++it) {
      int lc = it * 256 + tid;
      int m = lc >> 3, k8 = lc & 7;
      uint4 v = *(const uint4*)((const char*)A + ((long)(bm + m) * K + k0 + k8 * 8) * 2);
      *(uint4*)&As[(m * 8 + (k8 ^ (m & 7))) * 8] = v;
    }
    // stage B^T: 128 rows x 64 k (4 iters)
#pragma unroll
    for (int it = 0; it < 4; ++it) {
      int lc = it * 256 + tid;
      int n = lc >> 3, k8 = lc & 7;
      uint4 v = *(const uint4*)((const char*)Bp + ((long)(bn + n) * K + k0 + k8 * 8) * 2);
      *(uint4*)&Bs[(n * 8 + (k8 ^ (n & 7))) * 8] = v;
    }
    __syncthreads();
#pragma unroll
    for (int ks = 0; ks < 2; ++ks) {
      short8 af[MI], bfr[4];
#pragma unroll
      for (int mi = 0; mi < MI; ++mi) {
        int row = wm + mi * 16 + lm;
        af[mi] = *(const short8*)&As[row * 64 + ((ks * 4 + q) ^ (lm & 7)) * 8];
      }
#pragma unroll
      for (int ni = 0; ni < 4; ++ni) {
        int row = wn + ni * 16 + lm;
        bfr[ni] = *(const short8*)&Bs[row * 64 + ((ks * 4 + q) ^ (lm & 7)) * 8];
      }
#pragma unroll
      for (int mi = 0; mi < MI; ++mi)
#pragma unroll
        for (int ni = 0; ni < 4; ++ni)
          acc[mi][ni] = __builtin_amdgcn_mfma_f32_16x16x32_bf16(af[mi], bfr[ni], acc[mi][ni], 0, 0, 0);
    }
  }
  // epilogue: D[row][col], col=lane&15, row=q*4+reg
#pragma unroll
  for (int mi = 0; mi < MI; ++mi) {
#pragma unroll
    for (int ni = 0; ni < 4; ++ni) {
      int col = bn + wn + ni * 16 + lm;
      float bcol = bias[col];
#pragma unroll
      for (int r = 0; r < 4; ++r) {
        int row = bm + wm + mi * 16 + q * 4 + r;
        float v = acc[mi][ni][r] + bcol;
        if (SILU) v = siluf(v);
        if (XE) v *= xe[(row / 3) * HH + col];
        if (OUT_BF16) ((bf16*)Cout)[(long)row * N + col] = f2b(v);
        else ((float*)Cout)[(long)row * N + col] = v;
      }
    }
  }
}

// ---------------- sh = wig_node @ (o1 + o2) ----------------
__global__ __launch_bounds__(256) void rotback_kernel(
    const float* __restrict__ wig_node, const float* __restrict__ o1,
    const float* __restrict__ o2, float* __restrict__ sh) {
  __shared__ float wig[256];
  __shared__ float osum[2048];
  int e = blockIdx.x, tid = threadIdx.x;
  wig[tid] = wig_node[e * 256 + tid];
  for (int idx = tid; idx < 2048; idx += 256)
    osum[idx] = o1[(long)e * 2048 + idx] + o2[(long)e * 2048 + idx];
  __syncthreads();
  for (int idx = tid; idx < 2048; idx += 256) {
    int i = idx >> 7, c = idx & 127;
    float a = 0.f;
#pragma unroll
    for (int j = 0; j < 16; ++j) a += wig[i * 16 + j] * osum[j * 128 + c];
    sh[(long)e * 2048 + idx] = a;
  }
}

// ---------------- msg(bf16) = wigner @ z, z = 2(xs+xt) + asum + pad(sh) ----------------
__global__ __launch_bounds__(256) void rotate_msg_kernel(
    const float* __restrict__ x, const float* __restrict__ wigner,
    const int* __restrict__ eidx, const float* __restrict__ asum,
    const float* __restrict__ sh, bf16* __restrict__ msg) {
  __shared__ float z[49 * 128];
  __shared__ float wg[2352];
  __shared__ float as_s[49];
  int e = blockIdx.x, tid = threadIdx.x;
  int s = eidx[e], d = eidx[EE + e];
  if (tid < 49) as_s[tid] = asum[e * 49 + tid];
  for (int idx = tid; idx < 2352; idx += 256) wg[idx] = wigner[(long)e * 2352 + idx];
  __syncthreads();
  for (int idx = tid; idx < 6272; idx += 256) {
    int l = idx >> 7, c = idx & 127;
    float v = 2.0f * (x[((long)s * LL + l) * CC + c] + x[((long)d * LL + l) * CC + c]) + as_s[l];
    if (l < 16) v += sh[(long)e * 2048 + l * 128 + c];
    z[idx] = v;
  }
  __syncthreads();
  // one z-read serves all 3 NY accumulators
  for (int idx = tid; idx < 2048; idx += 256) {
    int r = idx >> 7, c = idx & 127;
    const float* w0 = wg + r * 49;
    float a0 = 0.f, a1 = 0.f, a2 = 0.f;
#pragma unroll 7
    for (int b = 0; b < 49; ++b) {
      float zv = z[b * 128 + c];
      a0 += w0[b] * zv;
      a1 += w0[784 + b] * zv;
      a2 += w0[1568 + b] * zv;
    }
    long base = (long)e * 3 * 2048 + r * 128 + c;
    msg[base] = f2b(a0);
    msg[base + 2048] = f2b(a1);
    msg[base + 4096] = f2b(a2);
  }
}

// ---------------- out = INV_SQRT_3 * wigner_inv @ mean_ny(m2) ----------------
__global__ __launch_bounds__(256) void out_kernel(
    const float* __restrict__ m2, const float* __restrict__ wigner_inv,
    float* __restrict__ out) {
  __shared__ float mr[2048];
  __shared__ float wv[784];
  int e = blockIdx.x, tid = threadIdx.x;
  for (int idx = tid; idx < 2048; idx += 256)
    mr[idx] = (m2[((long)e * 3 + 0) * 2048 + idx] + m2[((long)e * 3 + 1) * 2048 + idx] +
               m2[((long)e * 3 + 2) * 2048 + idx]) * (1.0f / 3.0f);
  for (int idx = tid; idx < 784; idx += 256) wv[idx] = wigner_inv[(long)e * 784 + idx];
  __syncthreads();
  for (int idx = tid; idx < 6272; idx += 256) {
    int bq = idx >> 7, c = idx & 127;
    const float* wp = wv + bq * 16;
    float a = 0.f;
#pragma unroll
    for (int r = 0; r < 16; ++r) a += wp[r] * mr[r * 128 + c];
    out[(long)e * 6272 + idx] = a * 0.57735026918962576f;
  }
}

// ---------------- host side ----------------
extern "C" void kernel_launch(void* const* d_in, const int* in_sizes, int n_in,
                              void* d_out, int out_size, void* d_ws, size_t ws_size,
                              hipStream_t stream) {
  (void)in_sizes; (void)n_in; (void)out_size; (void)ws_size;
  const float* x        = (const float*)d_in[0];
  const float* x_glovec = (const float*)d_in[2];
  const float* x_edge   = (const float*)d_in[3];
  const int*   eidx     = (const int*)d_in[4];
  const float* W_cg1   = (const float*)d_in[8];
  const float* W_cg21  = (const float*)d_in[9];
  const float* W_cg22  = (const float*)d_in[10];
  const float* Wn1a = (const float*)d_in[11];
  const float* bn1a = (const float*)d_in[12];
  const float* Wn1b = (const float*)d_in[13];
  const float* bn1b = (const float*)d_in[14];
  const float* Wn2a = (const float*)d_in[15];
  const float* bn2a = (const float*)d_in[16];
  const float* Wn2b = (const float*)d_in[17];
  const float* bn2b = (const float*)d_in[18];
  const float* Wd   = (const float*)d_in[19];
  const float* bd   = (const float*)d_in[20];
  const float* Wp1  = (const float*)d_in[21];
  const float* bp1  = (const float*)d_in[22];
  const float* Wp2  = (const float*)d_in[23];
  const float* bp2  = (const float*)d_in[24];
  const float* wigner     = (const float*)d_in[25];
  const float* wigner_inv = (const float*)d_in[26];
  const float* wig_node   = (const float*)d_in[27];

  char* W = (char*)d_ws;
  bf16*  featst = (bf16*)(W + 0);            // 8192 x 2112 bf16 (34.6 MB)
  float* ostack = (float*)(W + 34603008);    // 8192 x 2048 f32  (67 MB)
  float* m2     = (float*)(W + 0);           // alias: 12288 x 2048 f32 (100.7 MB <= 101.7)
  float* p_sh   = (float*)(W + 101711872);   // 4096 x 2048 f32
  bf16*  msg    = (bf16*)(W + 135266304);    // 12288 x 2048 bf16
  bf16*  hstack = (bf16*)(W + 185597952);    // 8192 x 128 bf16
  bf16*  m1     = (bf16*)(W + 187695104);    // 12288 x 128 bf16
  float* p_xe   = (float*)(W + 190840832);   // 4096 x 128 f32
  float* p_xmean= (float*)(W + 192937984);   // 100352 f32
  float* p_asum = (float*)(W + 193339392);   // 200704 f32
  bf16*  BTa    = (bf16*)(W + 194142208);    // 2 x 128 x 2112
  bf16*  BTb    = (bf16*)(W + 195223552);    // 2 x 2048 x 128
  bf16*  BTp1   = (bf16*)(W + 196272128);    // 128 x 2048
  bf16*  BTp2   = (bf16*)(W + 196796416);    // 2048 x 128

  TJobs tj;
  tj.j[0] = {Wn1a, BTa,            2064, 128, 2112};
  tj.j[1] = {Wn2a, BTa + 270336,   2064, 128, 2112};
  tj.j[2] = {Wn1b, BTb,            128, 2048, 128};
  tj.j[3] = {Wn2b, BTb + 262144,   128, 2048, 128};
  tj.j[4] = {Wp1,  BTp1,           2048, 128, 2048};
  tj.j[5] = {Wp2,  BTp2,           128, 2048, 128};
  transpose_cvt_kernel<<<dim3(1056, 6), 256, 0, stream>>>(tj);

  node_mean_kernel<<<(NN * LL) / 4, 256, 0, stream>>>(x, p_xmean);
  edge_scalar_kernel<<<EE / 4, 256, 0, stream>>>(p_xmean, eidx, W_cg1, W_cg21, W_cg22, p_asum);
  gemm_f32_silu<<<dim3(EE / 64, 2), 256, 0, stream>>>(x_edge, Wd, bd, p_xe, EE, HH, 128);
  build_feat_kernel<<<EE, 256, 0, stream>>>(x, x_glovec, wig_node, eidx, featst);
  // h = silu(feat @ Wna): M=8192, N=128, K=2112, stacked weights
  gemm_mfma<64, true, false, true><<<dim3(128, 1), 256, 0, stream>>>(
      featst, BTa, BTa + 270336, bn1a, bn2a, nullptr, hstack, 8192, 128, 2112, 4096);
  // o = silu(h @ Wnb): M=8192, N=2048, K=128, stacked weights, fp32 out
  gemm_mfma<128, true, false, false><<<dim3(64, 16), 256, 0, stream>>>(
      hstack, BTb, BTb + 262144, bn1b, bn2b, nullptr, ostack, 8192, 2048, 128, 4096);
  rotback_kernel<<<EE, 256, 0, stream>>>(wig_node, ostack, ostack + (long)4096 * 2048, p_sh);
  rotate_msg_kernel<<<EE, 256, 0, stream>>>(x, wigner, eidx, p_asum, p_sh, msg);
  // m1 = silu(msg @ Wp1) * xe: M=12288, N=128, K=2048, bf16 out
  gemm_mfma<64, true, true, true><<<dim3(192, 1), 256, 0, stream>>>(
      msg, BTp1, BTp1, bp1, bp1, p_xe, m1, 12288, 128, 2048, 1 << 30);
  // m2 = silu(m1 @ Wp2): M=12288, N=2048, K=128, fp32 out
  gemm_mfma<128, true, false, false><<<dim3(96, 16), 256, 0, stream>>>(
      m1, BTp2, BTp2, bp2, bp2, nullptr, m2, 12288, 2048, 128, 1 << 30);
  out_kernel<<<EE, 256, 0, stream>>>(m2, wigner_inv, (float*)d_out);
}

// Round 4
// 701.838 us; speedup vs baseline: 1.7550x; 1.0810x over previous
//
#include <hip/hip_runtime.h>
#include <hip/hip_bf16.h>

typedef __hip_bfloat16 bf16;
typedef __attribute__((ext_vector_type(8))) short short8;
typedef __attribute__((ext_vector_type(4))) float f32x4;

#define NN 2048
#define EE 4096
#define LL 49
#define LRR 16
#define NYY 3
#define CC 128
#define HH 128

#define K1P 2432   // 2401 padded to x64 (P1 / BT1 K)
#define K2P 2496   // 2450 padded to x64 (P2 / BT2 K)

__device__ __forceinline__ float siluf(float v) { return v * (1.0f / (1.0f + __expf(-v))); }
__device__ __forceinline__ bf16 f2b(float v) { return __float2bfloat16(v); }

// ---------------- weight convert + transpose: out[n*Kp+k] = bf16(in[k*N+n]), zero-pad k>=K ----------------
struct TJob { const float* in; bf16* out; int K, N, Kp; };
struct TJobs { TJob j[6]; };

__global__ __launch_bounds__(256) void transpose_cvt_kernel(TJobs jobs) {
  TJob jb = jobs.j[blockIdx.y];
  int i = blockIdx.x * 256 + threadIdx.x;
  if (i < jb.N * jb.Kp) {
    int n = i / jb.Kp, k = i - n * jb.Kp;
    jb.out[i] = (k < jb.K) ? f2b(jb.in[(long)k * jb.N + n]) : f2b(0.f);
  }
}

// ---------------- CG weight prep: BT1[32][K1P], BT2[64][K2P] (transposed, bf16, zero-padded) ----------------
__global__ __launch_bounds__(256) void cg_prep_kernel(
    const float* __restrict__ Wcg1, const float* __restrict__ Wcg21,
    const float* __restrict__ Wcg22, bf16* __restrict__ BT1, bf16* __restrict__ BT2) {
  int i = blockIdx.x * 256 + threadIdx.x;
  if (blockIdx.y == 0) {
    if (i < 32 * K1P) {
      int o = i / K1P, k = i - o * K1P;
      float v = (o < 25 && k < 2401) ? Wcg1[k * 25 + o] : 0.f;
      BT1[i] = f2b(v);
    }
  } else {
    if (i < 64 * K2P) {
      int o = i / K2P, k = i - o * K2P;
      float v = 0.f;
      if (o < 49) {
        if (k < 1225) v = Wcg21[k * 49 + o];
        else if (k < 2450) v = Wcg22[(k - 1225) * 49 + o];
      }
      BT2[i] = f2b(v);
    }
  }
}

// ---------------- per-node channel mean ----------------
__global__ __launch_bounds__(256) void node_mean_kernel(const float* __restrict__ x,
                                                        float* __restrict__ xmean) {
  int row = blockIdx.x * 4 + (threadIdx.x >> 6);
  int lane = threadIdx.x & 63;
  const float* p = x + (long)row * CC;
  float s = p[lane] + p[lane + 64];
  for (int off = 32; off > 0; off >>= 1) s += __shfl_down(s, off);
  if (lane == 0) xmean[row] = s * (1.0f / 128.0f);
}

// ---------------- P1[e][k] = xm_i * ym_j (k = i*49+j), bf16, zero-pad ----------------
__global__ __launch_bounds__(256) void build_p1_kernel(
    const float* __restrict__ xmean, const int* __restrict__ eidx, bf16* __restrict__ P1) {
  __shared__ float sxm[49], sym[49];
  int e = blockIdx.x, tid = threadIdx.x;
  int s = eidx[e], d = eidx[EE + e];
  if (tid < 49) { sxm[tid] = xmean[s * 49 + tid]; sym[tid] = xmean[d * 49 + tid]; }
  __syncthreads();
  for (int idx = tid; idx < K1P; idx += 256) {
    float v = 0.f;
    if (idx < 2401) { int i = idx / 49, j = idx - i * 49; v = sxm[i] * sym[j]; }
    P1[(long)e * K1P + idx] = f2b(v);
  }
}

// ---------------- P2[e][k]: k<1225: xm_i*mid_m; k<2450: ym_i*mid_m; pad 0 ----------------
__global__ __launch_bounds__(256) void build_p2_kernel(
    const float* __restrict__ xmean, const float* __restrict__ mid,
    const int* __restrict__ eidx, bf16* __restrict__ P2) {
  __shared__ float sxm[49], sym[49], smid[25];
  int e = blockIdx.x, tid = threadIdx.x;
  int s = eidx[e], d = eidx[EE + e];
  if (tid < 49) { sxm[tid] = xmean[s * 49 + tid]; sym[tid] = xmean[d * 49 + tid]; }
  if (tid >= 64 && tid < 89) smid[tid - 64] = mid[e * 32 + tid - 64];
  __syncthreads();
  for (int idx = tid; idx < K2P; idx += 256) {
    float v = 0.f;
    if (idx < 1225) { int i = idx / 25, m = idx - i * 25; v = sxm[i] * smid[m]; }
    else if (idx < 2450) { int kk = idx - 1225; int i = kk / 25, m = kk - i * 25; v = sym[i] * smid[m]; }
    P2[(long)e * K2P + idx] = f2b(v);
  }
}

// ---------------- small-N MFMA GEMM: C[M][NI*16] = A[M][K]bf16 @ BT[NI*16][K]^T ----------------
template <int NI>
__global__ __launch_bounds__(256) void gemm_smalln(
    const bf16* __restrict__ A, const bf16* __restrict__ BT,
    float* __restrict__ C, int K) {
  __shared__ short As[64 * 64];
  __shared__ short Bs[NI * 16 * 64];
  const int tid = threadIdx.x, w = tid >> 6, lane = tid & 63;
  const int lm = lane & 15, q = lane >> 4;
  const int bm = blockIdx.x * 64;
  f32x4 acc[NI];
#pragma unroll
  for (int ni = 0; ni < NI; ++ni) acc[ni] = (f32x4){0.f, 0.f, 0.f, 0.f};
  for (int k0 = 0; k0 < K; k0 += 64) {
    __syncthreads();
#pragma unroll
    for (int it = 0; it < 2; ++it) {
      int lc = it * 256 + tid;
      int m = lc >> 3, k8 = lc & 7;
      uint4 v = *(const uint4*)((const char*)A + ((long)(bm + m) * K + k0 + k8 * 8) * 2);
      *(uint4*)&As[(m * 8 + (k8 ^ (m & 7))) * 8] = v;
    }
#pragma unroll
    for (int it = 0; it < NI / 2; ++it) {
      int lc = it * 256 + tid;
      int n = lc >> 3, k8 = lc & 7;
      uint4 v = *(const uint4*)((const char*)BT + ((long)n * K + k0 + k8 * 8) * 2);
      *(uint4*)&Bs[(n * 8 + (k8 ^ (n & 7))) * 8] = v;
    }
    __syncthreads();
#pragma unroll
    for (int ks = 0; ks < 2; ++ks) {
      short8 af = *(const short8*)&As[(w * 16 + lm) * 64 + ((ks * 4 + q) ^ (lm & 7)) * 8];
#pragma unroll
      for (int ni = 0; ni < NI; ++ni) {
        short8 bfr = *(const short8*)&Bs[(ni * 16 + lm) * 64 + ((ks * 4 + q) ^ (lm & 7)) * 8];
        acc[ni] = __builtin_amdgcn_mfma_f32_16x16x32_bf16(af, bfr, acc[ni], 0, 0, 0);
      }
    }
  }
#pragma unroll
  for (int ni = 0; ni < NI; ++ni) {
    int col = ni * 16 + lm;
#pragma unroll
    for (int r = 0; r < 4; ++r) {
      int row = bm + w * 16 + q * 4 + r;
      C[(long)row * (NI * 16) + col] = acc[ni][r];
    }
  }
}

// ---------------- feat build -> bf16 [8192][2112] (rows e, 4096+e), pad cols 2064..2111 = 0 ----------------
__global__ __launch_bounds__(256) void build_feat_kernel(
    const float* __restrict__ x, const float* __restrict__ x_glovec,
    const float* __restrict__ wig_node, const int* __restrict__ eidx,
    bf16* __restrict__ featst) {
  __shared__ float wig[256];
  __shared__ float xa[2048], xb[2048], tmp[2048];
  int e = blockIdx.x, tid = threadIdx.x;
  int s = eidx[e], d = eidx[EE + e];
  wig[tid] = wig_node[e * 256 + tid];
  if (tid < 48) {
    featst[(long)e * 2112 + 2064 + tid] = f2b(0.f);
    featst[(long)(EE + e) * 2112 + 2064 + tid] = f2b(0.f);
  }
  for (int idx = tid; idx < 2048; idx += 256) {
    int l = idx >> 7, c = idx & 127;
    xa[idx] = x[((long)s * LL + l) * CC + c];
    xb[idx] = x[((long)d * LL + l) * CC + c];
  }
  __syncthreads();
  for (int idx = tid; idx < 2048; idx += 256) {
    int i = idx >> 7, c = idx & 127;
    float a = 0.f;
#pragma unroll
    for (int j = 0; j < 16; ++j) a += wig[j * 16 + i] * xa[j * 128 + c];
    tmp[idx] = a;
    featst[(long)e * 2112 + i * 129 + c] = f2b(a);
  }
  __syncthreads();
  if (tid < 16) {
    float m = 0.f;
    for (int c = 0; c < 128; ++c) m += tmp[tid * 128 + c];
    featst[(long)e * 2112 + tid * 129 + 128] = f2b(m * (1.0f / 128.0f) * x_glovec[(long)d * 16 + tid]);
  }
  __syncthreads();
  for (int idx = tid; idx < 2048; idx += 256) {
    int i = idx >> 7, c = idx & 127;
    float a = 0.f;
#pragma unroll
    for (int j = 0; j < 16; ++j) a += wig[j * 16 + i] * xb[j * 128 + c];
    tmp[idx] = a;
    featst[(long)(EE + e) * 2112 + i * 129 + c] = f2b(a);
  }
  __syncthreads();
  if (tid < 16) {
    float m = 0.f;
    for (int c = 0; c < 128; ++c) m += tmp[tid * 128 + c];
    featst[(long)(EE + e) * 2112 + tid * 129 + 128] = f2b(m * (1.0f / 128.0f) * x_glovec[(long)s * 16 + tid]);
  }
}

// ---------------- fp32 tiled GEMM (only for tiny xe GEMM) ----------------
__global__ __launch_bounds__(256) void gemm_f32_silu(
    const float* __restrict__ A, const float* __restrict__ B,
    const float* __restrict__ bias, float* __restrict__ C, int M, int N, int K) {
  __shared__ float As[16][68];
  __shared__ float Bs[16][64];
  const int tid = threadIdx.x;
  const int bm = blockIdx.x * 64, bn = blockIdx.y * 64;
  const int tx = tid & 15, ty = tid >> 4;
  const int ar = tid >> 2, ak = (tid & 3) * 4;
  const int br = tid >> 4, bc = (tid & 15) * 4;
  float acc[4][4] = {};
  const float* Ap = A + (long)(bm + ar) * K + ak;
  const float* Bp = B + (long)br * N + bn + bc;
  for (int k0 = 0; k0 < K; k0 += 16) {
    const float4 av = *(const float4*)(Ap + k0);
    const float4 bv = *(const float4*)(Bp + (long)k0 * N);
    __syncthreads();
    As[ak + 0][ar] = av.x; As[ak + 1][ar] = av.y;
    As[ak + 2][ar] = av.z; As[ak + 3][ar] = av.w;
    *(float4*)&Bs[br][bc] = bv;
    __syncthreads();
#pragma unroll
    for (int k = 0; k < 16; ++k) {
      const float4 a = *(const float4*)&As[k][ty * 4];
      const float4 b = *(const float4*)&Bs[k][tx * 4];
      acc[0][0] += a.x * b.x; acc[0][1] += a.x * b.y; acc[0][2] += a.x * b.z; acc[0][3] += a.x * b.w;
      acc[1][0] += a.y * b.x; acc[1][1] += a.y * b.y; acc[1][2] += a.y * b.z; acc[1][3] += a.y * b.w;
      acc[2][0] += a.z * b.x; acc[2][1] += a.z * b.y; acc[2][2] += a.z * b.z; acc[2][3] += a.z * b.w;
      acc[3][0] += a.w * b.x; acc[3][1] += a.w * b.y; acc[3][2] += a.w * b.z; acc[3][3] += a.w * b.w;
    }
  }
#pragma unroll
  for (int i = 0; i < 4; ++i) {
    int row = bm + ty * 4 + i;
#pragma unroll
    for (int j = 0; j < 4; ++j) {
      int col = bn + tx * 4 + j;
      C[(long)row * N + col] = siluf(acc[i][j] + bias[col]);
    }
  }
}

// ---------------- bf16 MFMA GEMM: C = epi(A[MxK]bf16 @ BT[NxK]bf16^T + bias) ----------------
template <int BM, bool SILU, bool XE, bool OUT_BF16>
__global__ __launch_bounds__(256) void gemm_mfma(
    const bf16* __restrict__ A, const bf16* __restrict__ B0, const bf16* __restrict__ B1,
    const float* __restrict__ bias0, const float* __restrict__ bias1,
    const float* __restrict__ xe, void* __restrict__ Cout,
    int M, int N, int K, int half) {
  constexpr int MI = BM / 32;
  __shared__ short As[BM * 64];
  __shared__ short Bs[128 * 64];
  const int tid = threadIdx.x;
  const int w = tid >> 6, lane = tid & 63;
  const int lm = lane & 15, q = lane >> 4;
  const int bm = blockIdx.x * BM, bn = blockIdx.y * 128;
  const int wm = (w & 1) * (BM / 2), wn = (w >> 1) * 64;
  const bf16* Bp = (bm < half) ? B0 : B1;
  const float* bias = (bm < half) ? bias0 : bias1;

  f32x4 acc[MI][4];
#pragma unroll
  for (int mi = 0; mi < MI; ++mi)
#pragma unroll
    for (int ni = 0; ni < 4; ++ni) acc[mi][ni] = (f32x4){0.f, 0.f, 0.f, 0.f};

  for (int k0 = 0; k0 < K; k0 += 64) {
    __syncthreads();
#pragma unroll
    for (int it = 0; it < BM / 32; ++it) {
      int lc = it * 256 + tid;
      int m = lc >> 3, k8 = lc & 7;
      uint4 v = *(const uint4*)((const char*)A + ((long)(bm + m) * K + k0 + k8 * 8) * 2);
      *(uint4*)&As[(m * 8 + (k8 ^ (m & 7))) * 8] = v;
    }
#pragma unroll
    for (int it = 0; it < 4; ++it) {
      int lc = it * 256 + tid;
      int n = lc >> 3, k8 = lc & 7;
      uint4 v = *(const uint4*)((const char*)Bp + ((long)(bn + n) * K + k0 + k8 * 8) * 2);
      *(uint4*)&Bs[(n * 8 + (k8 ^ (n & 7))) * 8] = v;
    }
    __syncthreads();
#pragma unroll
    for (int ks = 0; ks < 2; ++ks) {
      short8 af[MI], bfr[4];
#pragma unroll
      for (int mi = 0; mi < MI; ++mi) {
        int row = wm + mi * 16 + lm;
        af[mi] = *(const short8*)&As[row * 64 + ((ks * 4 + q) ^ (lm & 7)) * 8];
      }
#pragma unroll
      for (int ni = 0; ni < 4; ++ni) {
        int row = wn + ni * 16 + lm;
        bfr[ni] = *(const short8*)&Bs[row * 64 + ((ks * 4 + q) ^ (lm & 7)) * 8];
      }
#pragma unroll
      for (int mi = 0; mi < MI; ++mi)
#pragma unroll
        for (int ni = 0; ni < 4; ++ni)
          acc[mi][ni] = __builtin_amdgcn_mfma_f32_16x16x32_bf16(af[mi], bfr[ni], acc[mi][ni], 0, 0, 0);
    }
  }
#pragma unroll
  for (int mi = 0; mi < MI; ++mi) {
#pragma unroll
    for (int ni = 0; ni < 4; ++ni) {
      int col = bn + wn + ni * 16 + lm;
      float bcol = bias[col];
#pragma unroll
      for (int r = 0; r < 4; ++r) {
        int row = bm + wm + mi * 16 + q * 4 + r;
        float v = acc[mi][ni][r] + bcol;
        if (SILU) v = siluf(v);
        if (XE) v *= xe[(row / 3) * HH + col];
        if (OUT_BF16) ((bf16*)Cout)[(long)row * N + col] = f2b(v);
        else ((float*)Cout)[(long)row * N + col] = v;
      }
    }
  }
}

// ---------------- sh = wig_node @ (o1 + o2) ----------------
__global__ __launch_bounds__(256) void rotback_kernel(
    const float* __restrict__ wig_node, const float* __restrict__ o1,
    const float* __restrict__ o2, float* __restrict__ sh) {
  __shared__ float wig[256];
  __shared__ float osum[2048];
  int e = blockIdx.x, tid = threadIdx.x;
  wig[tid] = wig_node[e * 256 + tid];
  for (int idx = tid; idx < 2048; idx += 256)
    osum[idx] = o1[(long)e * 2048 + idx] + o2[(long)e * 2048 + idx];
  __syncthreads();
  for (int idx = tid; idx < 2048; idx += 256) {
    int i = idx >> 7, c = idx & 127;
    float a = 0.f;
#pragma unroll
    for (int j = 0; j < 16; ++j) a += wig[i * 16 + j] * osum[j * 128 + c];
    sh[(long)e * 2048 + idx] = a;
  }
}

// ---------------- msg(bf16) = wigner @ z, z = 2(xs+xt) + asum + pad(sh) ----------------
__global__ __launch_bounds__(256) void rotate_msg_kernel(
    const float* __restrict__ x, const float* __restrict__ wigner,
    const int* __restrict__ eidx, const float* __restrict__ asum,
    const float* __restrict__ sh, bf16* __restrict__ msg) {
  __shared__ float z[49 * 128];
  __shared__ float wg[2352];
  __shared__ float as_s[49];
  int e = blockIdx.x, tid = threadIdx.x;
  int s = eidx[e], d = eidx[EE + e];
  if (tid < 49) as_s[tid] = asum[e * 64 + tid];
  for (int idx = tid; idx < 2352; idx += 256) wg[idx] = wigner[(long)e * 2352 + idx];
  __syncthreads();
  for (int idx = tid; idx < 6272; idx += 256) {
    int l = idx >> 7, c = idx & 127;
    float v = 2.0f * (x[((long)s * LL + l) * CC + c] + x[((long)d * LL + l) * CC + c]) + as_s[l];
    if (l < 16) v += sh[(long)e * 2048 + l * 128 + c];
    z[idx] = v;
  }
  __syncthreads();
  for (int idx = tid; idx < 2048; idx += 256) {
    int r = idx >> 7, c = idx & 127;
    const float* w0 = wg + r * 49;
    float a0 = 0.f, a1 = 0.f, a2 = 0.f;
#pragma unroll 7
    for (int b = 0; b < 49; ++b) {
      float zv = z[b * 128 + c];
      a0 += w0[b] * zv;
      a1 += w0[784 + b] * zv;
      a2 += w0[1568 + b] * zv;
    }
    long base = (long)e * 3 * 2048 + r * 128 + c;
    msg[base] = f2b(a0);
    msg[base + 2048] = f2b(a1);
    msg[base + 4096] = f2b(a2);
  }
}

// ---------------- out = INV_SQRT_3 * wigner_inv @ mean_ny(m2) ----------------
__global__ __launch_bounds__(256) void out_kernel(
    const float* __restrict__ m2, const float* __restrict__ wigner_inv,
    float* __restrict__ out) {
  __shared__ float mr[2048];
  __shared__ float wv[784];
  int e = blockIdx.x, tid = threadIdx.x;
  for (int idx = tid; idx < 2048; idx += 256)
    mr[idx] = (m2[((long)e * 3 + 0) * 2048 + idx] + m2[((long)e * 3 + 1) * 2048 + idx] +
               m2[((long)e * 3 + 2) * 2048 + idx]) * (1.0f / 3.0f);
  for (int idx = tid; idx < 784; idx += 256) wv[idx] = wigner_inv[(long)e * 784 + idx];
  __syncthreads();
  for (int idx = tid; idx < 6272; idx += 256) {
    int bq = idx >> 7, c = idx & 127;
    const float* wp = wv + bq * 16;
    float a = 0.f;
#pragma unroll
    for (int r = 0; r < 16; ++r) a += wp[r] * mr[r * 128 + c];
    out[(long)e * 6272 + idx] = a * 0.57735026918962576f;
  }
}

// ---------------- host side ----------------
extern "C" void kernel_launch(void* const* d_in, const int* in_sizes, int n_in,
                              void* d_out, int out_size, void* d_ws, size_t ws_size,
                              hipStream_t stream) {
  (void)in_sizes; (void)n_in; (void)out_size; (void)ws_size;
  const float* x        = (const float*)d_in[0];
  const float* x_glovec = (const float*)d_in[2];
  const float* x_edge   = (const float*)d_in[3];
  const int*   eidx     = (const int*)d_in[4];
  const float* W_cg1   = (const float*)d_in[8];
  const float* W_cg21  = (const float*)d_in[9];
  const float* W_cg22  = (const float*)d_in[10];
  const float* Wn1a = (const float*)d_in[11];
  const float* bn1a = (const float*)d_in[12];
  const float* Wn1b = (const float*)d_in[13];
  const float* bn1b = (const float*)d_in[14];
  const float* Wn2a = (const float*)d_in[15];
  const float* bn2a = (const float*)d_in[16];
  const float* Wn2b = (const float*)d_in[17];
  const float* bn2b = (const float*)d_in[18];
  const float* Wd   = (const float*)d_in[19];
  const float* bd   = (const float*)d_in[20];
  const float* Wp1  = (const float*)d_in[21];
  const float* bp1  = (const float*)d_in[22];
  const float* Wp2  = (const float*)d_in[23];
  const float* bp2  = (const float*)d_in[24];
  const float* wigner     = (const float*)d_in[25];
  const float* wigner_inv = (const float*)d_in[26];
  const float* wig_node   = (const float*)d_in[27];

  char* W = (char*)d_ws;
  bf16*  featst = (bf16*)(W + 0);            // 8192 x 2112 bf16 (34.6 MB)
  float* ostack = (float*)(W + 34603008);    // 8192 x 2048 f32  (67 MB)
  float* m2     = (float*)(W + 0);           // alias: 12288 x 2048 f32 (100.7 MB)
  float* p_sh   = (float*)(W + 101711872);   // 4096 x 2048 f32
  bf16*  msg    = (bf16*)(W + 135266304);    // 12288 x 2048 bf16 (50.3 MB)
  bf16*  P1     = (bf16*)(W + 135266304);    // alias in msg region: 4096 x 2432 bf16 (19.9 MB)
  bf16*  P2     = (bf16*)(W + 155189248);    // alias in msg region: 4096 x 2496 bf16 (20.4 MB)
  bf16*  hstack = (bf16*)(W + 185597952);    // 8192 x 128 bf16
  bf16*  m1     = (bf16*)(W + 187695104);    // 12288 x 128 bf16
  float* p_xe   = (float*)(W + 190840832);   // 4096 x 128 f32
  float* p_xmean= (float*)(W + 192937984);   // 100352 f32
  bf16*  BTa    = (bf16*)(W + 194142208);    // 2 x 128 x 2112
  bf16*  BTb    = (bf16*)(W + 195223552);    // 2 x 2048 x 128
  bf16*  BTp1   = (bf16*)(W + 196272128);    // 128 x 2048
  bf16*  BTp2   = (bf16*)(W + 196796416);    // 2048 x 128 (ends 197320704)
  float* p_asum = (float*)(W + 197320704);   // 4096 x 64 f32 (1 MB)
  float* p_mid  = (float*)(W + 198369280);   // 4096 x 32 f32 (512 KB)
  bf16*  BT1    = (bf16*)(W + 198893568);    // 32 x 2432 bf16 (152 KB)
  bf16*  BT2    = (bf16*)(W + 199049216);    // 64 x 2496 bf16 (312 KB; ends 199368704)

  TJobs tj;
  tj.j[0] = {Wn1a, BTa,            2064, 128, 2112};
  tj.j[1] = {Wn2a, BTa + 270336,   2064, 128, 2112};
  tj.j[2] = {Wn1b, BTb,            128, 2048, 128};
  tj.j[3] = {Wn2b, BTb + 262144,   128, 2048, 128};
  tj.j[4] = {Wp1,  BTp1,           2048, 128, 2048};
  tj.j[5] = {Wp2,  BTp2,           128, 2048, 128};
  transpose_cvt_kernel<<<dim3(1056, 6), 256, 0, stream>>>(tj);
  cg_prep_kernel<<<dim3(624, 2), 256, 0, stream>>>(W_cg1, W_cg21, W_cg22, BT1, BT2);

  node_mean_kernel<<<(NN * LL) / 4, 256, 0, stream>>>(x, p_xmean);
  // CG bilinears as outer-product GEMMs
  build_p1_kernel<<<EE, 256, 0, stream>>>(p_xmean, eidx, P1);
  gemm_smalln<2><<<EE / 64, 256, 0, stream>>>(P1, BT1, p_mid, K1P);
  build_p2_kernel<<<EE, 256, 0, stream>>>(p_xmean, p_mid, eidx, P2);
  gemm_smalln<4><<<EE / 64, 256, 0, stream>>>(P2, BT2, p_asum, K2P);

  gemm_f32_silu<<<dim3(EE / 64, 2), 256, 0, stream>>>(x_edge, Wd, bd, p_xe, EE, HH, 128);
  build_feat_kernel<<<EE, 256, 0, stream>>>(x, x_glovec, wig_node, eidx, featst);
  // h = silu(feat @ Wna): M=8192, N=128, K=2112, stacked weights
  gemm_mfma<64, true, false, true><<<dim3(128, 1), 256, 0, stream>>>(
      featst, BTa, BTa + 270336, bn1a, bn2a, nullptr, hstack, 8192, 128, 2112, 4096);
  // o = silu(h @ Wnb): M=8192, N=2048, K=128, stacked weights, fp32 out
  gemm_mfma<128, true, false, false><<<dim3(64, 16), 256, 0, stream>>>(
      hstack, BTb, BTb + 262144, bn1b, bn2b, nullptr, ostack, 8192, 2048, 128, 4096);
  rotback_kernel<<<EE, 256, 0, stream>>>(wig_node, ostack, ostack + (long)4096 * 2048, p_sh);
  rotate_msg_kernel<<<EE, 256, 0, stream>>>(x, wigner, eidx, p_asum, p_sh, msg);
  // m1 = silu(msg @ Wp1) * xe: M=12288, N=128, K=2048, bf16 out
  gemm_mfma<64, true, true, true><<<dim3(192, 1), 256, 0, stream>>>(
      msg, BTp1, BTp1, bp1, bp1, p_xe, m1, 12288, 128, 2048, 1 << 30);
  // m2 = silu(m1 @ Wp2): M=12288, N=2048, K=128, fp32 out
  gemm_mfma<128, true, false, false><<<dim3(96, 16), 256, 0, stream>>>(
      m1, BTp2, BTp2, bp2, bp2, nullptr, m2, 12288, 2048, 128, 1 << 30);
  out_kernel<<<EE, 256, 0, stream>>>(m2, wigner_inv, (float*)d_out);
}